// Round 12
// baseline (334.360 us; speedup 1.0000x reference)
//
#include <hip/hip_runtime.h>
#include <hip/hip_bf16.h>
#include <stdint.h>

typedef float f32x4 __attribute__((ext_vector_type(4)));
typedef __bf16 bf16x8 __attribute__((ext_vector_type(8)));
typedef __bf16 bf16x4 __attribute__((ext_vector_type(4)));
typedef __bf16 bf16x2 __attribute__((ext_vector_type(2)));

#define NB 8
#define NC 192
#define NO 576
#define NH 128
#define NWID 128
#define NSP 16384
#define NHEADS 4
#define NCH 48

// workspace layout (bytes)
#define OFF_KV    0u
#define OFF_SSQ   12288u        // ssq 3072 f32 + S 73728 f32 contiguous (zeroed by k_prep)
#define OFF_S     24576u
#define OFF_WB    319488u       // 221184 B
#define OFF_M     540672u       // 589824 B
#define OFF_XT    1130496u      // xt 50331648 B; qkv2 aliases (xt dead after k_qkv): 150994944 B
#define OFF_QKV1  152125440u    // 150994944 B

#define GR(r) (((r) ^ ((r) >> 2)) & 7)

// async global->LDS DMA, 16B per lane; LDS dest is wave-uniform base + lane*16
__device__ __forceinline__ void g2l16(const void* g, void* l) {
    __builtin_amdgcn_global_load_lds((const __attribute__((address_space(1))) void*)g,
                                     (__attribute__((address_space(3))) void*)l, 16, 0, 0);
}

// rolling-row conv load: 2 px/lane + x-neighbors via shfl, zero-padded edges
#define LOADROW(SRC, Y, A, B, L_, R_) {                                       \
        bf16x2 p = {};                                                        \
        int y_ = (Y);                                                         \
        if (y_ >= 0 && y_ < NH) p = *reinterpret_cast<const bf16x2*>((SRC) + y_ * NWID + 2 * l); \
        A = (float)p[0]; B = (float)p[1];                                     \
        L_ = __shfl(B, l - 1); R_ = __shfl(A, l + 1);                         \
        if (l == 0) L_ = 0.f;                                                 \
        if (l == 63) R_ = 0.f; }

// ---------------- kernel 1: prep = zero(ssq,S) + Wb cast + kv GEMM ----------------
__global__ void k_prep(const float* __restrict__ prior, const float* __restrict__ w_kernel,
                       const float* __restrict__ w_qkv, float* __restrict__ kv,
                       float* __restrict__ zbase, __bf16* __restrict__ Wb) {
    int t = blockIdx.x * 256 + threadIdx.x;
    if (t < 76800) zbase[t] = 0.f;
    if (t < NO * NC) Wb[t] = (__bf16)w_qkv[t];
    if (t < NB * 384) {
        int b = t / 384, j = t % 384;
        const float* p = prior + b * NC;
        const float* wk = w_kernel + j * NC;
        float s = 0.f;
        for (int f = 0; f < NC; ++f) s += p[f] * wk[f];
        kv[t] = s;
    }
}

// ---------------- kernel 2: x~ = x*kv1 + kv2, transposed to [b][n][c] bf16 ----------------
__global__ __launch_bounds__(256) void k_xt(const float* __restrict__ x, const float* __restrict__ kv,
                                            __bf16* __restrict__ xt) {
    int b = blockIdx.y;
    int n0 = blockIdx.x * 128;
    __shared__ __align__(16) __bf16 lds[128 * 192];
    int t = threadIdx.x;
    for (int p = 0; p < 24; ++p) {
        int id = p * 256 + t;
        int c = id >> 5, n4 = (id & 31) << 2;
        f32x4 v = *reinterpret_cast<const f32x4*>(x + (size_t)(b * NC + c) * NSP + n0 + n4);
        float k1 = kv[b * 384 + c], k2 = kv[b * 384 + 192 + c];
        int chi = (c >> 3) ^ ((n4 >> 2) & 7);
        int base = chi * 16 + (c & 7) * 2;
#pragma unroll
        for (int j = 0; j < 4; ++j)
            *reinterpret_cast<__bf16*>((char*)lds + (n4 + j) * 384 + base) = (__bf16)(v[j] * k1 + k2);
    }
    __syncthreads();
    for (int p = 0; p < 12; ++p) {
        int id = p * 256 + t;
        int n = id / 24, k = id % 24;
        bf16x8 r = *reinterpret_cast<const bf16x8*>((char*)lds + n * 384 + ((k ^ ((n >> 2) & 7)) << 4));
        *reinterpret_cast<bf16x8*>(xt + (size_t)(b * NSP + n0 + n) * NC + k * 8) = r;
    }
}

// ---------------- kernel 3: qkv GEMM (r9-proven): B staged once via DMA, 9 A-tiles looped ----------------
__global__ __launch_bounds__(256, 2) void k_qkv(const __bf16* __restrict__ xt, const __bf16* __restrict__ Wb,
                                                __bf16* __restrict__ qkv1) {
    __shared__ __align__(16) char lds[73728];
    int b = blockIdx.y, n0 = blockIdx.x * 128;
    int t = threadIdx.x;
    const __bf16* bsrc = xt + (size_t)(b * NSP + n0) * NC;
#pragma unroll
    for (int i = 0; i < 12; ++i) {
        int s = i * 256 + t;
        int r = s / 24, c = s % 24, g = c ^ (r & 7);
        g2l16(bsrc + (size_t)r * NC + g * 8, lds + s * 16);
    }
#pragma unroll
    for (int i = 0; i < 6; ++i) {
        int s = i * 256 + t;
        int r = s / 24, c = s % 24, g = c ^ (r & 7);
        g2l16(Wb + (size_t)r * NC + g * 8, lds + 49152 + s * 16);
    }
    asm volatile("s_waitcnt vmcnt(0)" ::: "memory");
    __syncthreads();
    int w = t >> 6, l = t & 63, lr = l & 15, lg = l >> 4;
    bf16x8 bgf[6][2];
#pragma unroll
    for (int ks = 0; ks < 6; ++ks) {
        int c16 = ks * 4 + lg;
#pragma unroll
        for (int nf = 0; nf < 2; ++nf) {
            int r = w * 32 + nf * 16 + lr;
            bgf[ks][nf] = *reinterpret_cast<const bf16x8*>(lds + r * 384 + ((c16 ^ (r & 7)) << 4));
        }
    }
    for (int ot = 0; ot < 9; ++ot) {
        f32x4 acc[4][2] = {};
#pragma unroll
        for (int ks = 0; ks < 6; ++ks) {
            int c16 = ks * 4 + lg;
            bf16x8 a[4];
#pragma unroll
            for (int mf = 0; mf < 4; ++mf) {
                int r = mf * 16 + lr;
                a[mf] = *reinterpret_cast<const bf16x8*>(lds + 49152 + r * 384 + ((c16 ^ (r & 7)) << 4));
            }
#pragma unroll
            for (int mf = 0; mf < 4; ++mf)
#pragma unroll
                for (int nf = 0; nf < 2; ++nf)
                    acc[mf][nf] = __builtin_amdgcn_mfma_f32_16x16x32_bf16(a[mf], bgf[ks][nf], acc[mf][nf], 0, 0, 0);
        }
        __syncthreads();
        if (ot < 8) {
            const __bf16* asrc = Wb + (size_t)(ot + 1) * 64 * NC;
#pragma unroll
            for (int i = 0; i < 6; ++i) {
                int s = i * 256 + t;
                int r = s / 24, c = s % 24, g = c ^ (r & 7);
                g2l16(asrc + (size_t)r * NC + g * 8, lds + 49152 + s * 16);
            }
            __builtin_amdgcn_sched_barrier(0);
        }
        int o0 = ot * 64;
#pragma unroll
        for (int mf = 0; mf < 4; ++mf)
#pragma unroll
            for (int rr = 0; rr < 4; ++rr) {
                int orow = o0 + mf * 16 + lg * 4 + rr;
#pragma unroll
                for (int nf = 0; nf < 2; ++nf)
                    qkv1[(size_t)(b * NO + orow) * NSP + n0 + w * 32 + nf * 16 + lr] = (__bf16)acc[mf][nf][rr];
            }
        if (ot < 8) {
            asm volatile("s_waitcnt vmcnt(32)" ::: "memory");
            __syncthreads();
        }
    }
}

// ---------------- kernel 4: depthwise 3x3 conv, v channels only ----------------
__global__ __launch_bounds__(256) void k_dw(const __bf16* __restrict__ qkv1, const float* __restrict__ w_dw,
                                            __bf16* __restrict__ qkv2) {
    int task = blockIdx.x * 4 + (threadIdx.x >> 6);
    int l = threadIdx.x & 63;
    int strip = task & 7;
    int bo = task >> 3;            // 0..1535
    int o = 384 + (bo % 192), b = bo / 192;
    const __bf16* src = qkv1 + (size_t)(b * NO + o) * NSP;
    __bf16* dst = qkv2 + (size_t)(b * NO + o) * NSP;
    float wd[9];
#pragma unroll
    for (int i = 0; i < 9; ++i) wd[i] = w_dw[o * 9 + i];
    int ys = strip * 16;
    float a0, b0, L0, R0, a1, b1, L1, R1, a2, b2, L2, R2;
    LOADROW(src, ys - 1, a0, b0, L0, R0)
    LOADROW(src, ys,     a1, b1, L1, R1)
#pragma unroll 4
    for (int i = 0; i < 16; ++i) {
        LOADROW(src, ys + i + 1, a2, b2, L2, R2)
        float oa = L0 * wd[0] + a0 * wd[1] + b0 * wd[2]
                 + L1 * wd[3] + a1 * wd[4] + b1 * wd[5]
                 + L2 * wd[6] + a2 * wd[7] + b2 * wd[8];
        float ob = a0 * wd[0] + b0 * wd[1] + R0 * wd[2]
                 + a1 * wd[3] + b1 * wd[4] + R1 * wd[5]
                 + a2 * wd[6] + b2 * wd[7] + R2 * wd[8];
        bf16x2 ov; ov[0] = (__bf16)oa; ov[1] = (__bf16)ob;
        *reinterpret_cast<bf16x2*>(dst + (ys + i) * NWID + 2 * l) = ov;
        a0 = a1; b0 = b1; L0 = L1; R0 = R1;
        a1 = a2; b1 = b2; L1 = L2; R1 = R2;
    }
}

// ---------------- kernel 5: conv-fused Gram dots + ssq ----------------
// Block: (256-n chunk = image rows y0,y0+1) x head x batch.
// Phase A: k_dw-style conv of 96 q+k channels from qkv1 -> swizzled LDS [96][256] bf16 + ssq.
// Phase B: MFMA Gram on conv'd LDS; Phase C: cross-wave reduce + atomics to S.
__global__ __launch_bounds__(256, 3) void k_sdot(const __bf16* __restrict__ qkv1, const float* __restrict__ w_dw,
                                                 float* __restrict__ ssq, float* __restrict__ S) {
    __shared__ __align__(16) char lds[49152];
    int b = blockIdx.z, h = blockIdx.y, ct = blockIdx.x;
    int y0 = ct * 2;
    int t = threadIdx.x, w = t >> 6, l = t & 63, lr = l & 15, lg = l >> 4;
    // ---- Phase A: conv (wave w handles channels w, w+4, ..., w+92)
    for (int i = 0; i < 24; ++i) {
        int c = w + 4 * i;                                    // LDS row 0..95 (0-47 q, 48-95 k)
        int o = (c < 48) ? (h * NCH + c) : (192 + h * NCH + (c - 48));
        const __bf16* src = qkv1 + (size_t)(b * NO + o) * NSP;
        float wd[9];
#pragma unroll
        for (int k = 0; k < 9; ++k) wd[k] = w_dw[o * 9 + k];
        float a0, e0, L0, R0, a1, e1, L1, R1, a2, e2, L2, R2, a3, e3, L3, R3;
        LOADROW(src, y0 - 1, a0, e0, L0, R0)
        LOADROW(src, y0,     a1, e1, L1, R1)
        LOADROW(src, y0 + 1, a2, e2, L2, R2)
        LOADROW(src, y0 + 2, a3, e3, L3, R3)
        float oa = L0 * wd[0] + a0 * wd[1] + e0 * wd[2]
                 + L1 * wd[3] + a1 * wd[4] + e1 * wd[5]
                 + L2 * wd[6] + a2 * wd[7] + e2 * wd[8];
        float ob = a0 * wd[0] + e0 * wd[1] + R0 * wd[2]
                 + a1 * wd[3] + e1 * wd[4] + R1 * wd[5]
                 + a2 * wd[6] + e2 * wd[7] + R2 * wd[8];
        float oc = L1 * wd[0] + a1 * wd[1] + e1 * wd[2]
                 + L2 * wd[3] + a2 * wd[4] + e2 * wd[5]
                 + L3 * wd[6] + a3 * wd[7] + e3 * wd[8];
        float od = a1 * wd[0] + e1 * wd[1] + R1 * wd[2]
                 + a2 * wd[3] + e2 * wd[4] + R2 * wd[5]
                 + a3 * wd[6] + e3 * wd[7] + R3 * wd[8];
        bf16x2 ov0; ov0[0] = (__bf16)oa; ov0[1] = (__bf16)ob;
        bf16x2 ov1; ov1[0] = (__bf16)oc; ov1[1] = (__bf16)od;
        float ss = 0.f;
        { float f; f = (float)ov0[0]; ss += f * f; f = (float)ov0[1]; ss += f * f;
          f = (float)ov1[0]; ss += f * f; f = (float)ov1[1]; ss += f * f; }
        // swizzled LDS writes: row stride 512 B, slot = (n/8) ^ (c&7)
        int nl0 = 2 * l;
        int off0 = (nl0 & 7) * 2;
        *reinterpret_cast<bf16x2*>(lds + c * 512 + (((nl0 >> 3) ^ (c & 7)) << 4) + off0) = ov0;
        int nl1 = 128 + 2 * l;
        *reinterpret_cast<bf16x2*>(lds + c * 512 + (((nl1 >> 3) ^ (c & 7)) << 4) + off0) = ov1;
        for (int off = 32; off > 0; off >>= 1) ss += __shfl_down(ss, off);
        if (l == 0) atomicAdd(&ssq[b * 384 + o], ss);
    }
    __syncthreads();
    // ---- Phase B: Gram MFMA on conv'd LDS (each wave covers k-chunks (w*2+j)*4+lg)
    f32x4 acc[3][3] = {};
#pragma unroll
    for (int j = 0; j < 2; ++j) {
        int c16 = (w * 2 + j) * 4 + lg;   // 0..31
        bf16x8 a[3], bb[3];
#pragma unroll
        for (int mf = 0; mf < 3; ++mf) {
            int r = mf * 16 + lr;
            a[mf] = *reinterpret_cast<const bf16x8*>(lds + r * 512 + ((c16 ^ (r & 7)) << 4));
        }
#pragma unroll
        for (int nf = 0; nf < 3; ++nf) {
            int r = 48 + nf * 16 + lr;
            bb[nf] = *reinterpret_cast<const bf16x8*>(lds + r * 512 + ((c16 ^ (r & 7)) << 4));
        }
#pragma unroll
        for (int mf = 0; mf < 3; ++mf)
#pragma unroll
            for (int nf = 0; nf < 3; ++nf)
                acc[mf][nf] = __builtin_amdgcn_mfma_f32_16x16x32_bf16(a[mf], bb[nf], acc[mf][nf], 0, 0, 0);
    }
    __syncthreads();
    // ---- Phase C: cross-wave reduce + atomics
    float* red = (float*)lds;
#pragma unroll
    for (int mf = 0; mf < 3; ++mf)
#pragma unroll
        for (int nf = 0; nf < 3; ++nf)
#pragma unroll
            for (int r = 0; r < 4; ++r) {
                int c = mf * 16 + lg * 4 + r, d = nf * 16 + lr;
                red[(w * 48 + c) * 49 + d] = acc[mf][nf][r];
            }
    __syncthreads();
    float* Sb = S + (size_t)(b * NHEADS + h) * NCH * NCH;
    for (int i = 0; i < 9; ++i) {
        int idx = t + i * 256;
        int c = idx / 48, d = idx % 48;
        float s = red[c * 49 + d] + red[(48 + c) * 49 + d] + red[(96 + c) * 49 + d] + red[(144 + c) * 49 + d];
        atomicAdd(&Sb[c * 48 + d], s);
    }
}

// ---------------- kernel 6: normalize + softmax + fold proj ----------------
__global__ __launch_bounds__(256) void k_soft(const float* __restrict__ S, const float* __restrict__ ssq,
                                              const float* __restrict__ temp, const float* __restrict__ w_proj,
                                              __bf16* __restrict__ M) {
    int b = blockIdx.x / NHEADS, h = blockIdx.x % NHEADS;
    int tid = threadIdx.x;
    __shared__ float attn[48][48];
    __shared__ float inv[96];
    if (tid < 96) {
        int c = tid % 48;
        int isK = tid / 48;
        float v = ssq[b * 384 + isK * 192 + h * NCH + c];
        float nrm = fmaxf(sqrtf(v), 1e-12f);
        inv[tid] = 1.f / nrm;
    }
    __syncthreads();
    float tp = temp[h];
    const float* Sb = S + (size_t)(b * NHEADS + h) * NCH * NCH;
    for (int i = 0; i < 9; ++i) {
        int idx = tid + i * 256;
        int c = idx / 48, d = idx % 48;
        attn[c][d] = Sb[c * 48 + d] * inv[c] * inv[48 + d] * tp;
    }
    __syncthreads();
    if (tid < 48) {
        float m = -1e30f;
        for (int d = 0; d < 48; ++d) m = fmaxf(m, attn[tid][d]);
        float sum = 0.f;
        for (int d = 0; d < 48; ++d) { float e = __expf(attn[tid][d] - m); attn[tid][d] = e; sum += e; }
        float r = 1.f / sum;
        for (int d = 0; d < 48; ++d) attn[tid][d] *= r;
    }
    __syncthreads();
    for (int i = 0; i < 36; ++i) {
        int idx = tid + i * 256;
        int oo = idx / 48, d = idx % 48;
        const float* wp = w_proj + oo * NC + h * NCH;
        float s = 0.f;
        for (int c = 0; c < 48; ++c) s += wp[c] * attn[c][d];
        M[(size_t)(b * NC + oo) * NC + h * NCH + d] = (__bf16)s;
    }
}

// ---------------- kernel 7: final GEMM, fused v-transpose staging, 3 A-tiles looped ----------------
__global__ __launch_bounds__(256, 2) void k_out(const __bf16* __restrict__ Mw, const __bf16* __restrict__ qkv2,
                                                float* __restrict__ outp) {
    __shared__ __align__(16) char lds[73728];
    int b = blockIdx.y, n0 = blockIdx.x * 128;
    int t = threadIdx.x;
    const __bf16* asrc0 = Mw + (size_t)(b * NC) * NC;
#pragma unroll
    for (int i = 0; i < 6; ++i) {
        int s = i * 256 + t;
        int r = s / 24, c = s % 24, g = c ^ GR(r);
        g2l16(asrc0 + (size_t)r * NC + g * 8, lds + 49152 + s * 16);
    }
    const __bf16* vb = qkv2 + (size_t)(b * NO + 384) * NSP + n0;
#pragma unroll 4
    for (int p = 0; p < 24; ++p) {
        int id = p * 256 + t;
        int c = id >> 5, n4 = (id & 31) << 2;
        bf16x4 vv = *reinterpret_cast<const bf16x4*>(vb + (size_t)c * NSP + n4);
#pragma unroll
        for (int j = 0; j < 4; ++j) {
            int n = n4 + j;
            int chi = (c >> 3) ^ GR(n);
            *reinterpret_cast<__bf16*>((char*)lds + n * 384 + chi * 16 + (c & 7) * 2) = vv[j];
        }
    }
    asm volatile("s_waitcnt vmcnt(0)" ::: "memory");
    __syncthreads();
    int w = t >> 6, l = t & 63, lr = l & 15, lg = l >> 4;
    bf16x8 bgf[6][2];
#pragma unroll
    for (int ks = 0; ks < 6; ++ks) {
        int c16 = ks * 4 + lg;
#pragma unroll
        for (int nf = 0; nf < 2; ++nf) {
            int r = w * 32 + nf * 16 + lr;
            bgf[ks][nf] = *reinterpret_cast<const bf16x8*>(lds + r * 384 + ((c16 ^ GR(r)) << 4));
        }
    }
    for (int ot = 0; ot < 3; ++ot) {
        f32x4 acc[4][2] = {};
#pragma unroll
        for (int ks = 0; ks < 6; ++ks) {
            int c16 = ks * 4 + lg;
            bf16x8 a[4];
#pragma unroll
            for (int mf = 0; mf < 4; ++mf) {
                int r = mf * 16 + lr;
                a[mf] = *reinterpret_cast<const bf16x8*>(lds + 49152 + r * 384 + ((c16 ^ GR(r)) << 4));
            }
#pragma unroll
            for (int mf = 0; mf < 4; ++mf)
#pragma unroll
                for (int nf = 0; nf < 2; ++nf)
                    acc[mf][nf] = __builtin_amdgcn_mfma_f32_16x16x32_bf16(a[mf], bgf[ks][nf], acc[mf][nf], 0, 0, 0);
        }
        __syncthreads();
        if (ot < 2) {
            const __bf16* asrc = Mw + (size_t)(b * NC + (ot + 1) * 64) * NC;
#pragma unroll
            for (int i = 0; i < 6; ++i) {
                int s = i * 256 + t;
                int r = s / 24, c = s % 24, g = c ^ GR(r);
                g2l16(asrc + (size_t)r * NC + g * 8, lds + 49152 + s * 16);
            }
            __builtin_amdgcn_sched_barrier(0);
        }
        int o0 = ot * 64;
#pragma unroll
        for (int mf = 0; mf < 4; ++mf)
#pragma unroll
            for (int rr = 0; rr < 4; ++rr) {
                int orow = o0 + mf * 16 + lg * 4 + rr;
#pragma unroll
                for (int nf = 0; nf < 2; ++nf)
                    outp[(size_t)(b * NC + orow) * NSP + n0 + w * 32 + nf * 16 + lr] = acc[mf][nf][rr];
            }
        if (ot < 2) {
            asm volatile("s_waitcnt vmcnt(32)" ::: "memory");
            __syncthreads();
        }
    }
}

extern "C" void kernel_launch(void* const* d_in, const int* in_sizes, int n_in,
                              void* d_out, int out_size, void* d_ws, size_t ws_size,
                              hipStream_t stream) {
    const float* x        = (const float*)d_in[0];
    const float* prior    = (const float*)d_in[1];
    const float* w_qkv    = (const float*)d_in[2];
    const float* w_dw     = (const float*)d_in[3];
    const float* w_proj   = (const float*)d_in[4];
    const float* w_kernel = (const float*)d_in[5];
    const float* temp     = (const float*)d_in[6];
    char* ws = (char*)d_ws;
    float*  kv    = (float*)(ws + OFF_KV);
    float*  ssq   = (float*)(ws + OFF_SSQ);
    float*  S     = (float*)(ws + OFF_S);
    __bf16* Wb    = (__bf16*)(ws + OFF_WB);
    __bf16* M     = (__bf16*)(ws + OFF_M);
    __bf16* xt    = (__bf16*)(ws + OFF_XT);
    __bf16* qkv2  = (__bf16*)(ws + OFF_XT);    // aliases xt (xt dead after k_qkv); only v region used
    __bf16* qkv1  = (__bf16*)(ws + OFF_QKV1);
    float*  outp  = (float*)d_out;

    k_prep<<<432, 256, 0, stream>>>(prior, w_kernel, w_qkv, kv, (float*)(ws + OFF_SSQ), Wb);
    k_xt<<<dim3(128, 8), 256, 0, stream>>>(x, kv, xt);
    k_qkv<<<dim3(128, 8), 256, 0, stream>>>(xt, Wb, qkv1);
    k_dw<<<3072, 256, 0, stream>>>(qkv1, w_dw, qkv2);
    k_sdot<<<dim3(64, 4, 8), 256, 0, stream>>>(qkv1, w_dw, ssq, S);
    k_soft<<<32, 256, 0, stream>>>(S, ssq, temp, w_proj, M);
    k_out<<<dim3(128, 8), 256, 0, stream>>>(M, qkv2, outp);
}

// Round 13
// 315.600 us; speedup vs baseline: 1.0594x; 1.0594x over previous
//
#include <hip/hip_runtime.h>
#include <hip/hip_bf16.h>
#include <stdint.h>

typedef float f32x4 __attribute__((ext_vector_type(4)));
typedef __bf16 bf16x8 __attribute__((ext_vector_type(8)));
typedef __bf16 bf16x4 __attribute__((ext_vector_type(4)));
typedef __bf16 bf16x2 __attribute__((ext_vector_type(2)));

#define NB 8
#define NC 192
#define NO 576
#define NH 128
#define NWID 128
#define NSP 16384
#define NHEADS 4
#define NCH 48

// workspace layout (bytes)
#define OFF_KV    0u
#define OFF_SSQ   12288u        // ssq 3072 f32 + S 73728 f32 contiguous (zeroed by k_prep)
#define OFF_S     24576u
#define OFF_WB    319488u       // 221184 B
#define OFF_M     540672u       // 589824 B
#define OFF_XT    1130496u      // xt 50331648 B; qkv2 aliases (xt dead after k_qkv): 150994944 B
#define OFF_QKV1  152125440u    // 150994944 B

#define GR(r) (((r) ^ ((r) >> 2)) & 7)

// async global->LDS DMA, 16B per lane; LDS dest is wave-uniform base + lane*16
__device__ __forceinline__ void g2l16(const void* g, void* l) {
    __builtin_amdgcn_global_load_lds((const __attribute__((address_space(1))) void*)g,
                                     (__attribute__((address_space(3))) void*)l, 16, 0, 0);
}

// rolling-row conv load: 2 px/lane + x-neighbors via shfl, zero-padded edges
#define LOADROW(SRC, Y, A, B, L_, R_) {                                       \
        bf16x2 p = {};                                                        \
        int y_ = (Y);                                                         \
        if (y_ >= 0 && y_ < NH) p = *reinterpret_cast<const bf16x2*>((SRC) + y_ * NWID + 2 * l); \
        A = (float)p[0]; B = (float)p[1];                                     \
        L_ = __shfl(B, l - 1); R_ = __shfl(A, l + 1);                         \
        if (l == 0) L_ = 0.f;                                                 \
        if (l == 63) R_ = 0.f; }

// ---------------- kernel 1: prep = zero(ssq,S) + Wb cast + kv GEMM ----------------
__global__ void k_prep(const float* __restrict__ prior, const float* __restrict__ w_kernel,
                       const float* __restrict__ w_qkv, float* __restrict__ kv,
                       float* __restrict__ zbase, __bf16* __restrict__ Wb) {
    int t = blockIdx.x * 256 + threadIdx.x;
    if (t < 76800) zbase[t] = 0.f;
    if (t < NO * NC) Wb[t] = (__bf16)w_qkv[t];
    if (t < NB * 384) {
        int b = t / 384, j = t % 384;
        const float* p = prior + b * NC;
        const float* wk = w_kernel + j * NC;
        float s = 0.f;
        for (int f = 0; f < NC; ++f) s += p[f] * wk[f];
        kv[t] = s;
    }
}

// ---------------- kernel 2: x~ = x*kv1 + kv2, transposed to [b][n][c] bf16 ----------------
__global__ __launch_bounds__(256) void k_xt(const float* __restrict__ x, const float* __restrict__ kv,
                                            __bf16* __restrict__ xt) {
    int b = blockIdx.y;
    int n0 = blockIdx.x * 128;
    __shared__ __align__(16) __bf16 lds[128 * 192];
    int t = threadIdx.x;
    for (int p = 0; p < 24; ++p) {
        int id = p * 256 + t;
        int c = id >> 5, n4 = (id & 31) << 2;
        f32x4 v = *reinterpret_cast<const f32x4*>(x + (size_t)(b * NC + c) * NSP + n0 + n4);
        float k1 = kv[b * 384 + c], k2 = kv[b * 384 + 192 + c];
        int chi = (c >> 3) ^ ((n4 >> 2) & 7);
        int base = chi * 16 + (c & 7) * 2;
#pragma unroll
        for (int j = 0; j < 4; ++j)
            *reinterpret_cast<__bf16*>((char*)lds + (n4 + j) * 384 + base) = (__bf16)(v[j] * k1 + k2);
    }
    __syncthreads();
    for (int p = 0; p < 12; ++p) {
        int id = p * 256 + t;
        int n = id / 24, k = id % 24;
        bf16x8 r = *reinterpret_cast<const bf16x8*>((char*)lds + n * 384 + ((k ^ ((n >> 2) & 7)) << 4));
        *reinterpret_cast<bf16x8*>(xt + (size_t)(b * NSP + n0 + n) * NC + k * 8) = r;
    }
}

// ---------------- kernel 3: qkv GEMM, BARRIER-FREE wave-autonomous ----------------
// Block = (nsub, ot, b). A-frags (64o x 192k) in REGISTERS (24 bf16x8/lane from L2-hot Wb).
// B wave-private: wave w DMAs only its 16 n-rows into its own 2x6KB LDS dbuf region.
// No __syncthreads anywhere; counted vmcnt only.
__global__ __launch_bounds__(256, 3) void k_qkv(const __bf16* __restrict__ xt, const __bf16* __restrict__ Wb,
                                                __bf16* __restrict__ qkv1) {
    __shared__ __align__(16) char lds[49152];   // 4 waves x 2 bufs x 6144 B
    int b = blockIdx.z, ot = blockIdx.y;
    int nbase = blockIdx.x * 1024;
    int t = threadIdx.x, w = t >> 6, l = t & 63, lr = l & 15, lg = l >> 4;
    char* wlds = lds + w * 12288;
    // B(0) DMA first (oldest in vmcnt order)
    const __bf16* bsrc0 = xt + (size_t)(b * NSP + nbase + w * 16) * NC;
#pragma unroll
    for (int j = 0; j < 6; ++j) {
        int s = j * 64 + l;
        int r = s / 24, c = s % 24, g = c ^ (r & 7);
        g2l16(bsrc0 + (size_t)r * NC + g * 8, wlds + s * 16);
    }
    // A fragments direct from global into registers (96 VGPR)
    const __bf16* asrc = Wb + (size_t)(ot * 64 + lr) * NC + lg * 8;
    bf16x8 ag[4][6];
#pragma unroll
    for (int mf = 0; mf < 4; ++mf)
#pragma unroll
        for (int ks = 0; ks < 6; ++ks)
            ag[mf][ks] = *reinterpret_cast<const bf16x8*>(asrc + (size_t)mf * 16 * NC + ks * 32);
    for (int i = 0; i < 16; ++i) {
        int cur = i & 1;
        if (i < 15) {   // prefetch B(i+1) into other buffer
            const __bf16* bsrc = xt + (size_t)(b * NSP + nbase + (i + 1) * 64 + w * 16) * NC;
#pragma unroll
            for (int j = 0; j < 6; ++j) {
                int s = j * 64 + l;
                int r = s / 24, c = s % 24, g = c ^ (r & 7);
                g2l16(bsrc + (size_t)r * NC + g * 8, wlds + (cur ^ 1) * 6144 + s * 16);
            }
            __builtin_amdgcn_sched_barrier(0);   // pin DMA issue before stores below
        }
        // wait for B(i): it is the oldest DMA group among outstanding ops.
        // i=0: outstanding = B0(6,old) + A(24) + B1(6) -> vmcnt(30)
        // 1<=i<15: B(i)(6,old) among <= {older-stores drained} + st(i-1)16 + B(i+1)6 -> vmcnt(22)
        // i=15: B15(6,old) + st(14)(16) -> vmcnt(16)
        if (i == 0)      asm volatile("s_waitcnt vmcnt(30)" ::: "memory");
        else if (i < 15) asm volatile("s_waitcnt vmcnt(22)" ::: "memory");
        else             asm volatile("s_waitcnt vmcnt(16)" ::: "memory");
        f32x4 acc[4] = {};
#pragma unroll
        for (int ks = 0; ks < 6; ++ks) {
            bf16x8 bg = *reinterpret_cast<const bf16x8*>(
                wlds + cur * 6144 + lr * 384 + (((ks * 4 + lg) ^ (lr & 7)) << 4));
#pragma unroll
            for (int mf = 0; mf < 4; ++mf)
                acc[mf] = __builtin_amdgcn_mfma_f32_16x16x32_bf16(ag[mf][ks], bg, acc[mf], 0, 0, 0);
        }
        int n = nbase + i * 64 + w * 16 + lr;
#pragma unroll
        for (int mf = 0; mf < 4; ++mf)
#pragma unroll
            for (int rr = 0; rr < 4; ++rr) {
                int orow = ot * 64 + mf * 16 + lg * 4 + rr;
                qkv1[(size_t)(b * NO + orow) * NSP + n] = (__bf16)acc[mf][rr];
            }
    }
}

// ---------------- kernel 4: depthwise 3x3 conv + sumsq(q,k), register-rolling ----------------
__global__ __launch_bounds__(256) void k_dw(const __bf16* __restrict__ qkv1, const float* __restrict__ w_dw,
                                            __bf16* __restrict__ qkv2, float* __restrict__ ssq) {
    int task = blockIdx.x * 4 + (threadIdx.x >> 6);
    int l = threadIdx.x & 63;
    int strip = task & 7;
    int bo = task >> 3;
    int o = bo % NO, b = bo / NO;
    const __bf16* src = qkv1 + (size_t)bo * NSP;
    __bf16* dst = qkv2 + (size_t)bo * NSP;
    float wd[9];
#pragma unroll
    for (int i = 0; i < 9; ++i) wd[i] = w_dw[o * 9 + i];
    int ys = strip * 16;
    float a0, b0, L0, R0, a1, b1, L1, R1, a2, b2, L2, R2;
    LOADROW(src, ys - 1, a0, b0, L0, R0)
    LOADROW(src, ys,     a1, b1, L1, R1)
    float ss = 0.f;
    bool qk = (o < 384);
#pragma unroll 4
    for (int i = 0; i < 16; ++i) {
        LOADROW(src, ys + i + 1, a2, b2, L2, R2)
        float oa = L0 * wd[0] + a0 * wd[1] + b0 * wd[2]
                 + L1 * wd[3] + a1 * wd[4] + b1 * wd[5]
                 + L2 * wd[6] + a2 * wd[7] + b2 * wd[8];
        float ob = a0 * wd[0] + b0 * wd[1] + R0 * wd[2]
                 + a1 * wd[3] + b1 * wd[4] + R1 * wd[5]
                 + a2 * wd[6] + b2 * wd[7] + R2 * wd[8];
        bf16x2 ov; ov[0] = (__bf16)oa; ov[1] = (__bf16)ob;
        *reinterpret_cast<bf16x2*>(dst + (ys + i) * NWID + 2 * l) = ov;
        if (qk) { float fa = (float)ov[0], fb = (float)ov[1]; ss += fa * fa + fb * fb; }
        a0 = a1; b0 = b1; L0 = L1; R0 = R1;
        a1 = a2; b1 = b2; L1 = L2; R1 = R2;
    }
    if (qk) {
        for (int off = 32; off > 0; off >>= 1) ss += __shfl_down(ss, off);
        if (l == 0) atomicAdd(&ssq[b * 384 + o], ss);
    }
}

// ---------------- kernel 5: Gram dots, staged 2-pass (r9-proven); S += q.k^T over n-chunk 512 ----------------
__global__ __launch_bounds__(256, 3) void k_sdot(const __bf16* __restrict__ qkv2, float* __restrict__ S) {
    __shared__ __align__(16) char lds[49152];
    int b = blockIdx.z, h = blockIdx.y, n0 = blockIdx.x * 512;
    int t = threadIdx.x;
    int w = t >> 6, l = t & 63, lr = l & 15, lg = l >> 4;
    const __bf16* qsrc = qkv2 + (size_t)(b * NO + h * NCH) * NSP + n0;
    const __bf16* ksrc = qkv2 + (size_t)(b * NO + 192 + h * NCH) * NSP + n0;
    f32x4 acc[3][3] = {};
    for (int pass = 0; pass < 2; ++pass) {
        if (pass) __syncthreads();
        int coff = pass * 256;
#pragma unroll
        for (int i = 0; i < 6; ++i) {
            int s = i * 256 + t;
            int r = s >> 5, c = s & 31, g = c ^ (r & 7);
            g2l16(qsrc + (size_t)r * NSP + coff + g * 8, lds + s * 16);
        }
#pragma unroll
        for (int i = 0; i < 6; ++i) {
            int s = i * 256 + t;
            int r = s >> 5, c = s & 31, g = c ^ (r & 7);
            g2l16(ksrc + (size_t)r * NSP + coff + g * 8, lds + 24576 + s * 16);
        }
        asm volatile("s_waitcnt vmcnt(0)" ::: "memory");
        __syncthreads();
#pragma unroll
        for (int j = 0; j < 2; ++j) {
            int c16 = (w * 2 + j) * 4 + lg;
            bf16x8 a[3], bb[3];
#pragma unroll
            for (int mf = 0; mf < 3; ++mf) {
                int r = mf * 16 + lr;
                a[mf] = *reinterpret_cast<const bf16x8*>(lds + r * 512 + ((c16 ^ (r & 7)) << 4));
            }
#pragma unroll
            for (int nf = 0; nf < 3; ++nf) {
                int r = nf * 16 + lr;
                bb[nf] = *reinterpret_cast<const bf16x8*>(lds + 24576 + r * 512 + ((c16 ^ (r & 7)) << 4));
            }
#pragma unroll
            for (int mf = 0; mf < 3; ++mf)
#pragma unroll
                for (int nf = 0; nf < 3; ++nf)
                    acc[mf][nf] = __builtin_amdgcn_mfma_f32_16x16x32_bf16(a[mf], bb[nf], acc[mf][nf], 0, 0, 0);
        }
    }
    __syncthreads();
    float* red = (float*)lds;
#pragma unroll
    for (int mf = 0; mf < 3; ++mf)
#pragma unroll
        for (int nf = 0; nf < 3; ++nf)
#pragma unroll
            for (int r = 0; r < 4; ++r) {
                int c = mf * 16 + lg * 4 + r, d = nf * 16 + lr;
                red[(w * 48 + c) * 49 + d] = acc[mf][nf][r];
            }
    __syncthreads();
    float* Sb = S + (size_t)(b * NHEADS + h) * NCH * NCH;
    for (int i = 0; i < 9; ++i) {
        int idx = t + i * 256;
        int c = idx / 48, d = idx % 48;
        float s = red[c * 49 + d] + red[(48 + c) * 49 + d] + red[(96 + c) * 49 + d] + red[(144 + c) * 49 + d];
        atomicAdd(&Sb[c * 48 + d], s);
    }
}

// ---------------- kernel 6: normalize + softmax + fold proj ----------------
__global__ __launch_bounds__(256) void k_soft(const float* __restrict__ S, const float* __restrict__ ssq,
                                              const float* __restrict__ temp, const float* __restrict__ w_proj,
                                              __bf16* __restrict__ M) {
    int b = blockIdx.x / NHEADS, h = blockIdx.x % NHEADS;
    int tid = threadIdx.x;
    __shared__ float attn[48][48];
    __shared__ float inv[96];
    if (tid < 96) {
        int c = tid % 48;
        int isK = tid / 48;
        float v = ssq[b * 384 + isK * 192 + h * NCH + c];
        float nrm = fmaxf(sqrtf(v), 1e-12f);
        inv[tid] = 1.f / nrm;
    }
    __syncthreads();
    float tp = temp[h];
    const float* Sb = S + (size_t)(b * NHEADS + h) * NCH * NCH;
    for (int i = 0; i < 9; ++i) {
        int idx = tid + i * 256;
        int c = idx / 48, d = idx % 48;
        attn[c][d] = Sb[c * 48 + d] * inv[c] * inv[48 + d] * tp;
    }
    __syncthreads();
    if (tid < 48) {
        float m = -1e30f;
        for (int d = 0; d < 48; ++d) m = fmaxf(m, attn[tid][d]);
        float sum = 0.f;
        for (int d = 0; d < 48; ++d) { float e = __expf(attn[tid][d] - m); attn[tid][d] = e; sum += e; }
        float r = 1.f / sum;
        for (int d = 0; d < 48; ++d) attn[tid][d] *= r;
    }
    __syncthreads();
    for (int i = 0; i < 36; ++i) {
        int idx = tid + i * 256;
        int oo = idx / 48, d = idx % 48;
        const float* wp = w_proj + oo * NC + h * NCH;
        float s = 0.f;
        for (int c = 0; c < 48; ++c) s += wp[c] * attn[c][d];
        M[(size_t)(b * NC + oo) * NC + h * NCH + d] = (__bf16)s;
    }
}

// ---------------- kernel 7: final GEMM, fused v-transpose staging, 3 A-tiles looped ----------------
__global__ __launch_bounds__(256, 2) void k_out(const __bf16* __restrict__ Mw, const __bf16* __restrict__ qkv2,
                                                float* __restrict__ outp) {
    __shared__ __align__(16) char lds[73728];
    int b = blockIdx.y, n0 = blockIdx.x * 128;
    int t = threadIdx.x;
    const __bf16* asrc0 = Mw + (size_t)(b * NC) * NC;
#pragma unroll
    for (int i = 0; i < 6; ++i) {
        int s = i * 256 + t;
        int r = s / 24, c = s % 24, g = c ^ GR(r);
        g2l16(asrc0 + (size_t)r * NC + g * 8, lds + 49152 + s * 16);
    }
    const __bf16* vb = qkv2 + (size_t)(b * NO + 384) * NSP + n0;
#pragma unroll 4
    for (int p = 0; p < 24; ++p) {
        int id = p * 256 + t;
        int c = id >> 5, n4 = (id & 31) << 2;
        bf16x4 vv = *reinterpret_cast<const bf16x4*>(vb + (size_t)c * NSP + n4);
#pragma unroll
        for (int j = 0; j < 4; ++j) {
            int n = n4 + j;
            int chi = (c >> 3) ^ GR(n);
            *reinterpret_cast<__bf16*>((char*)lds + n * 384 + chi * 16 + (c & 7) * 2) = vv[j];
        }
    }
    asm volatile("s_waitcnt vmcnt(0)" ::: "memory");
    __syncthreads();
    int w = t >> 6, l = t & 63, lr = l & 15, lg = l >> 4;
    bf16x8 bgf[6][2];
#pragma unroll
    for (int ks = 0; ks < 6; ++ks) {
        int c16 = ks * 4 + lg;
#pragma unroll
        for (int nf = 0; nf < 2; ++nf) {
            int r = w * 32 + nf * 16 + lr;
            bgf[ks][nf] = *reinterpret_cast<const bf16x8*>(lds + r * 384 + ((c16 ^ GR(r)) << 4));
        }
    }
    for (int ot = 0; ot < 3; ++ot) {
        f32x4 acc[4][2] = {};
#pragma unroll
        for (int ks = 0; ks < 6; ++ks) {
            int c16 = ks * 4 + lg;
            bf16x8 a[4];
#pragma unroll
            for (int mf = 0; mf < 4; ++mf) {
                int r = mf * 16 + lr;
                a[mf] = *reinterpret_cast<const bf16x8*>(lds + 49152 + r * 384 + ((c16 ^ GR(r)) << 4));
            }
#pragma unroll
            for (int mf = 0; mf < 4; ++mf)
#pragma unroll
                for (int nf = 0; nf < 2; ++nf)
                    acc[mf][nf] = __builtin_amdgcn_mfma_f32_16x16x32_bf16(a[mf], bgf[ks][nf], acc[mf][nf], 0, 0, 0);
        }
        __syncthreads();
        if (ot < 2) {
            const __bf16* asrc = Mw + (size_t)(b * NC + (ot + 1) * 64) * NC;
#pragma unroll
            for (int i = 0; i < 6; ++i) {
                int s = i * 256 + t;
                int r = s / 24, c = s % 24, g = c ^ GR(r);
                g2l16(asrc + (size_t)r * NC + g * 8, lds + 49152 + s * 16);
            }
            __builtin_amdgcn_sched_barrier(0);
        }
        int o0 = ot * 64;
#pragma unroll
        for (int mf = 0; mf < 4; ++mf)
#pragma unroll
            for (int rr = 0; rr < 4; ++rr) {
                int orow = o0 + mf * 16 + lg * 4 + rr;
#pragma unroll
                for (int nf = 0; nf < 2; ++nf)
                    outp[(size_t)(b * NC + orow) * NSP + n0 + w * 32 + nf * 16 + lr] = acc[mf][nf][rr];
            }
        if (ot < 2) {
            asm volatile("s_waitcnt vmcnt(32)" ::: "memory");
            __syncthreads();
        }
    }
}

extern "C" void kernel_launch(void* const* d_in, const int* in_sizes, int n_in,
                              void* d_out, int out_size, void* d_ws, size_t ws_size,
                              hipStream_t stream) {
    const float* x        = (const float*)d_in[0];
    const float* prior    = (const float*)d_in[1];
    const float* w_qkv    = (const float*)d_in[2];
    const float* w_dw     = (const float*)d_in[3];
    const float* w_proj   = (const float*)d_in[4];
    const float* w_kernel = (const float*)d_in[5];
    const float* temp     = (const float*)d_in[6];
    char* ws = (char*)d_ws;
    float*  kv    = (float*)(ws + OFF_KV);
    float*  ssq   = (float*)(ws + OFF_SSQ);
    float*  S     = (float*)(ws + OFF_S);
    __bf16* Wb    = (__bf16*)(ws + OFF_WB);
    __bf16* M     = (__bf16*)(ws + OFF_M);
    __bf16* xt    = (__bf16*)(ws + OFF_XT);
    __bf16* qkv2  = (__bf16*)(ws + OFF_XT);    // aliases xt (xt dead after k_qkv)
    __bf16* qkv1  = (__bf16*)(ws + OFF_QKV1);
    float*  outp  = (float*)d_out;

    k_prep<<<432, 256, 0, stream>>>(prior, w_kernel, w_qkv, kv, (float*)(ws + OFF_SSQ), Wb);
    k_xt<<<dim3(128, 8), 256, 0, stream>>>(x, kv, xt);
    k_qkv<<<dim3(16, 9, 8), 256, 0, stream>>>(xt, Wb, qkv1);
    k_dw<<<9216, 256, 0, stream>>>(qkv1, w_dw, qkv2, ssq);
    k_sdot<<<dim3(32, 4, 8), 256, 0, stream>>>(qkv2, S);
    k_soft<<<32, 256, 0, stream>>>(S, ssq, temp, w_proj, M);
    k_out<<<dim3(128, 8), 256, 0, stream>>>(M, qkv2, outp);
}

// Round 14
// 226.379 us; speedup vs baseline: 1.4770x; 1.3941x over previous
//
#include <hip/hip_runtime.h>
#include <hip/hip_bf16.h>
#include <stdint.h>

typedef float f32x4 __attribute__((ext_vector_type(4)));
typedef __bf16 bf16x8 __attribute__((ext_vector_type(8)));
typedef __bf16 bf16x4 __attribute__((ext_vector_type(4)));
typedef __bf16 bf16x2 __attribute__((ext_vector_type(2)));

#define NB 8
#define NC 192
#define NO 576
#define NH 128
#define NWID 128
#define NSP 16384
#define NHEADS 4
#define NCH 48

// workspace layout (bytes) -- r9-proven
#define OFF_KV    0u
#define OFF_SSQ   12288u        // ssq 3072 f32 + S 73728 f32 contiguous (zeroed by k_prep)
#define OFF_S     24576u
#define OFF_WB    319488u       // 221184 B
#define OFF_M     540672u       // 589824 B
#define OFF_XT    1130496u      // xt 50331648 B; qkv2 aliases (xt dead after k_qkv): 150994944 B
#define OFF_QKV1  152125440u    // 150994944 B

#define GR(r) (((r) ^ ((r) >> 2)) & 7)

// async global->LDS DMA, 16B per lane; LDS dest is wave-uniform base + lane*16
__device__ __forceinline__ void g2l16(const void* g, void* l) {
    __builtin_amdgcn_global_load_lds((const __attribute__((address_space(1))) void*)g,
                                     (__attribute__((address_space(3))) void*)l, 16, 0, 0);
}

// rolling-row conv load: 2 px/lane + x-neighbors via shfl, zero-padded edges
#define LOADROW(SRC, Y, A, B, L_, R_) {                                       \
        bf16x2 p = {};                                                        \
        int y_ = (Y);                                                         \
        if (y_ >= 0 && y_ < NH) p = *reinterpret_cast<const bf16x2*>((SRC) + y_ * NWID + 2 * l); \
        A = (float)p[0]; B = (float)p[1];                                     \
        L_ = __shfl(B, l - 1); R_ = __shfl(A, l + 1);                         \
        if (l == 0) L_ = 0.f;                                                 \
        if (l == 63) R_ = 0.f; }

// ---------------- kernel 1: prep = zero(ssq,S) + Wb cast + kv GEMM ----------------
__global__ void k_prep(const float* __restrict__ prior, const float* __restrict__ w_kernel,
                       const float* __restrict__ w_qkv, float* __restrict__ kv,
                       float* __restrict__ zbase, __bf16* __restrict__ Wb) {
    int t = blockIdx.x * 256 + threadIdx.x;
    if (t < 76800) zbase[t] = 0.f;
    if (t < NO * NC) Wb[t] = (__bf16)w_qkv[t];
    if (t < NB * 384) {
        int b = t / 384, j = t % 384;
        const float* p = prior + b * NC;
        const float* wk = w_kernel + j * NC;
        float s = 0.f;
        for (int f = 0; f < NC; ++f) s += p[f] * wk[f];
        kv[t] = s;
    }
}

// ---------------- kernel 2: x~ = x*kv1 + kv2, transposed to [b][n][c] bf16 ----------------
__global__ __launch_bounds__(256) void k_xt(const float* __restrict__ x, const float* __restrict__ kv,
                                            __bf16* __restrict__ xt) {
    int b = blockIdx.y;
    int n0 = blockIdx.x * 128;
    __shared__ __align__(16) __bf16 lds[128 * 192];
    int t = threadIdx.x;
    for (int p = 0; p < 24; ++p) {
        int id = p * 256 + t;
        int c = id >> 5, n4 = (id & 31) << 2;
        f32x4 v = *reinterpret_cast<const f32x4*>(x + (size_t)(b * NC + c) * NSP + n0 + n4);
        float k1 = kv[b * 384 + c], k2 = kv[b * 384 + 192 + c];
        int chi = (c >> 3) ^ ((n4 >> 2) & 7);
        int base = chi * 16 + (c & 7) * 2;
#pragma unroll
        for (int j = 0; j < 4; ++j)
            *reinterpret_cast<__bf16*>((char*)lds + (n4 + j) * 384 + base) = (__bf16)(v[j] * k1 + k2);
    }
    __syncthreads();
    for (int p = 0; p < 12; ++p) {
        int id = p * 256 + t;
        int n = id / 24, k = id % 24;
        bf16x8 r = *reinterpret_cast<const bf16x8*>((char*)lds + n * 384 + ((k ^ ((n >> 2) & 7)) << 4));
        *reinterpret_cast<bf16x8*>(xt + (size_t)(b * NSP + n0 + n) * NC + k * 8) = r;
    }
}

// ---------------- kernel 3: qkv GEMM (r9-proven): B staged once via DMA, 9 A-tiles looped ----------------
// B tile (xt) 128x192 bf16 = 48KB at lds[0]; A tile (Wb) 64x192 = 24KB at lds[49152].
// LDS slot (r, c) holds global chunk (c ^ (r&7)); read side applies same XOR.
__global__ __launch_bounds__(256, 2) void k_qkv(const __bf16* __restrict__ xt, const __bf16* __restrict__ Wb,
                                                __bf16* __restrict__ qkv1) {
    __shared__ __align__(16) char lds[73728];
    int b = blockIdx.y, n0 = blockIdx.x * 128;
    int t = threadIdx.x;
    const __bf16* bsrc = xt + (size_t)(b * NSP + n0) * NC;
#pragma unroll
    for (int i = 0; i < 12; ++i) {
        int s = i * 256 + t;
        int r = s / 24, c = s % 24, g = c ^ (r & 7);
        g2l16(bsrc + (size_t)r * NC + g * 8, lds + s * 16);
    }
#pragma unroll
    for (int i = 0; i < 6; ++i) {
        int s = i * 256 + t;
        int r = s / 24, c = s % 24, g = c ^ (r & 7);
        g2l16(Wb + (size_t)r * NC + g * 8, lds + 49152 + s * 16);
    }
    asm volatile("s_waitcnt vmcnt(0)" ::: "memory");
    __syncthreads();
    int w = t >> 6, l = t & 63, lr = l & 15, lg = l >> 4;
    bf16x8 bgf[6][2];
#pragma unroll
    for (int ks = 0; ks < 6; ++ks) {
        int c16 = ks * 4 + lg;
#pragma unroll
        for (int nf = 0; nf < 2; ++nf) {
            int r = w * 32 + nf * 16 + lr;
            bgf[ks][nf] = *reinterpret_cast<const bf16x8*>(lds + r * 384 + ((c16 ^ (r & 7)) << 4));
        }
    }
    for (int ot = 0; ot < 9; ++ot) {
        f32x4 acc[4][2] = {};
#pragma unroll
        for (int ks = 0; ks < 6; ++ks) {
            int c16 = ks * 4 + lg;
            bf16x8 a[4];
#pragma unroll
            for (int mf = 0; mf < 4; ++mf) {
                int r = mf * 16 + lr;
                a[mf] = *reinterpret_cast<const bf16x8*>(lds + 49152 + r * 384 + ((c16 ^ (r & 7)) << 4));
            }
#pragma unroll
            for (int mf = 0; mf < 4; ++mf)
#pragma unroll
                for (int nf = 0; nf < 2; ++nf)
                    acc[mf][nf] = __builtin_amdgcn_mfma_f32_16x16x32_bf16(a[mf], bgf[ks][nf], acc[mf][nf], 0, 0, 0);
        }
        __syncthreads();              // all waves done reading A(ot)
        if (ot < 8) {
            const __bf16* asrc = Wb + (size_t)(ot + 1) * 64 * NC;
#pragma unroll
            for (int i = 0; i < 6; ++i) {
                int s = i * 256 + t;
                int r = s / 24, c = s % 24, g = c ^ (r & 7);
                g2l16(asrc + (size_t)r * NC + g * 8, lds + 49152 + s * 16);
            }
        }
        int o0 = ot * 64;
#pragma unroll
        for (int mf = 0; mf < 4; ++mf)
#pragma unroll
            for (int rr = 0; rr < 4; ++rr) {
                int orow = o0 + mf * 16 + lg * 4 + rr;
#pragma unroll
                for (int nf = 0; nf < 2; ++nf)
                    qkv1[(size_t)(b * NO + orow) * NSP + n0 + w * 32 + nf * 16 + lr] = (__bf16)acc[mf][nf][rr];
            }
        if (ot < 8) {
            // 6 DMAs issued first, then 32 stores: vmcnt(32) => 6 oldest (DMAs) retired
            asm volatile("s_waitcnt vmcnt(32)" ::: "memory");
            __syncthreads();
        }
    }
}

// ---------------- kernel 4: depthwise 3x3 conv + sumsq(q,k), register-rolling ----------------
__global__ __launch_bounds__(256) void k_dw(const __bf16* __restrict__ qkv1, const float* __restrict__ w_dw,
                                            __bf16* __restrict__ qkv2, float* __restrict__ ssq) {
    int task = blockIdx.x * 4 + (threadIdx.x >> 6);
    int l = threadIdx.x & 63;
    int strip = task & 7;
    int bo = task >> 3;
    int o = bo % NO, b = bo / NO;
    const __bf16* src = qkv1 + (size_t)bo * NSP;
    __bf16* dst = qkv2 + (size_t)bo * NSP;
    float wd[9];
#pragma unroll
    for (int i = 0; i < 9; ++i) wd[i] = w_dw[o * 9 + i];
    int ys = strip * 16;
    float a0, b0, L0, R0, a1, b1, L1, R1, a2, b2, L2, R2;
    LOADROW(src, ys - 1, a0, b0, L0, R0)
    LOADROW(src, ys,     a1, b1, L1, R1)
    float ss = 0.f;
    bool qk = (o < 384);
#pragma unroll 4
    for (int i = 0; i < 16; ++i) {
        LOADROW(src, ys + i + 1, a2, b2, L2, R2)
        float oa = L0 * wd[0] + a0 * wd[1] + b0 * wd[2]
                 + L1 * wd[3] + a1 * wd[4] + b1 * wd[5]
                 + L2 * wd[6] + a2 * wd[7] + b2 * wd[8];
        float ob = a0 * wd[0] + b0 * wd[1] + R0 * wd[2]
                 + a1 * wd[3] + b1 * wd[4] + R1 * wd[5]
                 + a2 * wd[6] + b2 * wd[7] + R2 * wd[8];
        bf16x2 ov; ov[0] = (__bf16)oa; ov[1] = (__bf16)ob;
        *reinterpret_cast<bf16x2*>(dst + (ys + i) * NWID + 2 * l) = ov;
        if (qk) { float fa = (float)ov[0], fb = (float)ov[1]; ss += fa * fa + fb * fb; }
        a0 = a1; b0 = b1; L0 = L1; R0 = R1;
        a1 = a2; b1 = b2; L1 = L2; R1 = R2;
    }
    if (qk) {
        for (int off = 32; off > 0; off >>= 1) ss += __shfl_down(ss, off);
        if (l == 0) atomicAdd(&ssq[b * 384 + o], ss);
    }
}

// ---------------- kernel 5: Gram dots, staged 2-pass (r9-proven); S += q.k^T over n-chunk 512 ----------------
__global__ __launch_bounds__(256, 3) void k_sdot(const __bf16* __restrict__ qkv2, float* __restrict__ S) {
    __shared__ __align__(16) char lds[49152];
    int b = blockIdx.z, h = blockIdx.y, n0 = blockIdx.x * 512;
    int t = threadIdx.x;
    int w = t >> 6, l = t & 63, lr = l & 15, lg = l >> 4;
    const __bf16* qsrc = qkv2 + (size_t)(b * NO + h * NCH) * NSP + n0;
    const __bf16* ksrc = qkv2 + (size_t)(b * NO + 192 + h * NCH) * NSP + n0;
    f32x4 acc[3][3] = {};
    for (int pass = 0; pass < 2; ++pass) {
        if (pass) __syncthreads();
        int coff = pass * 256;
#pragma unroll
        for (int i = 0; i < 6; ++i) {
            int s = i * 256 + t;
            int r = s >> 5, c = s & 31, g = c ^ (r & 7);
            g2l16(qsrc + (size_t)r * NSP + coff + g * 8, lds + s * 16);
        }
#pragma unroll
        for (int i = 0; i < 6; ++i) {
            int s = i * 256 + t;
            int r = s >> 5, c = s & 31, g = c ^ (r & 7);
            g2l16(ksrc + (size_t)r * NSP + coff + g * 8, lds + 24576 + s * 16);
        }
        asm volatile("s_waitcnt vmcnt(0)" ::: "memory");
        __syncthreads();
#pragma unroll
        for (int j = 0; j < 2; ++j) {
            int c16 = (w * 2 + j) * 4 + lg;
            bf16x8 a[3], bb[3];
#pragma unroll
            for (int mf = 0; mf < 3; ++mf) {
                int r = mf * 16 + lr;
                a[mf] = *reinterpret_cast<const bf16x8*>(lds + r * 512 + ((c16 ^ (r & 7)) << 4));
            }
#pragma unroll
            for (int nf = 0; nf < 3; ++nf) {
                int r = nf * 16 + lr;
                bb[nf] = *reinterpret_cast<const bf16x8*>(lds + 24576 + r * 512 + ((c16 ^ (r & 7)) << 4));
            }
#pragma unroll
            for (int mf = 0; mf < 3; ++mf)
#pragma unroll
                for (int nf = 0; nf < 3; ++nf)
                    acc[mf][nf] = __builtin_amdgcn_mfma_f32_16x16x32_bf16(a[mf], bb[nf], acc[mf][nf], 0, 0, 0);
        }
    }
    __syncthreads();
    float* red = (float*)lds;
#pragma unroll
    for (int mf = 0; mf < 3; ++mf)
#pragma unroll
        for (int nf = 0; nf < 3; ++nf)
#pragma unroll
            for (int r = 0; r < 4; ++r) {
                int c = mf * 16 + lg * 4 + r, d = nf * 16 + lr;
                red[(w * 48 + c) * 49 + d] = acc[mf][nf][r];
            }
    __syncthreads();
    float* Sb = S + (size_t)(b * NHEADS + h) * NCH * NCH;
    for (int i = 0; i < 9; ++i) {
        int idx = t + i * 256;
        int c = idx / 48, d = idx % 48;
        float s = red[c * 49 + d] + red[(48 + c) * 49 + d] + red[(96 + c) * 49 + d] + red[(144 + c) * 49 + d];
        atomicAdd(&Sb[c * 48 + d], s);
    }
}

// ---------------- kernel 6: normalize + softmax + fold proj ----------------
__global__ __launch_bounds__(256) void k_soft(const float* __restrict__ S, const float* __restrict__ ssq,
                                              const float* __restrict__ temp, const float* __restrict__ w_proj,
                                              __bf16* __restrict__ M) {
    int b = blockIdx.x / NHEADS, h = blockIdx.x % NHEADS;
    int tid = threadIdx.x;
    __shared__ float attn[48][48];
    __shared__ float inv[96];
    if (tid < 96) {
        int c = tid % 48;
        int isK = tid / 48;
        float v = ssq[b * 384 + isK * 192 + h * NCH + c];
        float nrm = fmaxf(sqrtf(v), 1e-12f);
        inv[tid] = 1.f / nrm;
    }
    __syncthreads();
    float tp = temp[h];
    const float* Sb = S + (size_t)(b * NHEADS + h) * NCH * NCH;
    for (int i = 0; i < 9; ++i) {
        int idx = tid + i * 256;
        int c = idx / 48, d = idx % 48;
        attn[c][d] = Sb[c * 48 + d] * inv[c] * inv[48 + d] * tp;
    }
    __syncthreads();
    if (tid < 48) {
        float m = -1e30f;
        for (int d = 0; d < 48; ++d) m = fmaxf(m, attn[tid][d]);
        float sum = 0.f;
        for (int d = 0; d < 48; ++d) { float e = __expf(attn[tid][d] - m); attn[tid][d] = e; sum += e; }
        float r = 1.f / sum;
        for (int d = 0; d < 48; ++d) attn[tid][d] *= r;
    }
    __syncthreads();
    for (int i = 0; i < 36; ++i) {
        int idx = tid + i * 256;
        int oo = idx / 48, d = idx % 48;
        const float* wp = w_proj + oo * NC + h * NCH;
        float s = 0.f;
        for (int c = 0; c < 48; ++c) s += wp[c] * attn[c][d];
        M[(size_t)(b * NC + oo) * NC + h * NCH + d] = (__bf16)s;
    }
}

// ---------------- kernel 7: final GEMM, fused v-transpose staging, 3 A-tiles looped ----------------
__global__ __launch_bounds__(256, 2) void k_out(const __bf16* __restrict__ Mw, const __bf16* __restrict__ qkv2,
                                                float* __restrict__ outp) {
    __shared__ __align__(16) char lds[73728];
    int b = blockIdx.y, n0 = blockIdx.x * 128;
    int t = threadIdx.x;
    const __bf16* asrc0 = Mw + (size_t)(b * NC) * NC;
#pragma unroll
    for (int i = 0; i < 6; ++i) {
        int s = i * 256 + t;
        int r = s / 24, c = s % 24, g = c ^ GR(r);
        g2l16(asrc0 + (size_t)r * NC + g * 8, lds + 49152 + s * 16);
    }
    // B-tile: bf16x4 loads along n, scalar swizzled LDS writes
    const __bf16* vb = qkv2 + (size_t)(b * NO + 384) * NSP + n0;
#pragma unroll 4
    for (int p = 0; p < 24; ++p) {
        int id = p * 256 + t;
        int c = id >> 5, n4 = (id & 31) << 2;
        bf16x4 vv = *reinterpret_cast<const bf16x4*>(vb + (size_t)c * NSP + n4);
#pragma unroll
        for (int j = 0; j < 4; ++j) {
            int n = n4 + j;
            int chi = (c >> 3) ^ GR(n);
            *reinterpret_cast<__bf16*>((char*)lds + n * 384 + chi * 16 + (c & 7) * 2) = vv[j];
        }
    }
    asm volatile("s_waitcnt vmcnt(0)" ::: "memory");
    __syncthreads();
    int w = t >> 6, l = t & 63, lr = l & 15, lg = l >> 4;
    bf16x8 bgf[6][2];
#pragma unroll
    for (int ks = 0; ks < 6; ++ks) {
        int c16 = ks * 4 + lg;
#pragma unroll
        for (int nf = 0; nf < 2; ++nf) {
            int r = w * 32 + nf * 16 + lr;
            bgf[ks][nf] = *reinterpret_cast<const bf16x8*>(lds + r * 384 + ((c16 ^ GR(r)) << 4));
        }
    }
    for (int ot = 0; ot < 3; ++ot) {
        f32x4 acc[4][2] = {};
#pragma unroll
        for (int ks = 0; ks < 6; ++ks) {
            int c16 = ks * 4 + lg;
            bf16x8 a[4];
#pragma unroll
            for (int mf = 0; mf < 4; ++mf) {
                int r = mf * 16 + lr;
                a[mf] = *reinterpret_cast<const bf16x8*>(lds + 49152 + r * 384 + ((c16 ^ GR(r)) << 4));
            }
#pragma unroll
            for (int mf = 0; mf < 4; ++mf)
#pragma unroll
                for (int nf = 0; nf < 2; ++nf)
                    acc[mf][nf] = __builtin_amdgcn_mfma_f32_16x16x32_bf16(a[mf], bgf[ks][nf], acc[mf][nf], 0, 0, 0);
        }
        __syncthreads();
        if (ot < 2) {
            const __bf16* asrc = Mw + (size_t)(b * NC + (ot + 1) * 64) * NC;
#pragma unroll
            for (int i = 0; i < 6; ++i) {
                int s = i * 256 + t;
                int r = s / 24, c = s % 24, g = c ^ GR(r);
                g2l16(asrc + (size_t)r * NC + g * 8, lds + 49152 + s * 16);
            }
        }
        int o0 = ot * 64;
#pragma unroll
        for (int mf = 0; mf < 4; ++mf)
#pragma unroll
            for (int rr = 0; rr < 4; ++rr) {
                int orow = o0 + mf * 16 + lg * 4 + rr;
#pragma unroll
                for (int nf = 0; nf < 2; ++nf)
                    outp[(size_t)(b * NC + orow) * NSP + n0 + w * 32 + nf * 16 + lr] = acc[mf][nf][rr];
            }
        if (ot < 2) {
            asm volatile("s_waitcnt vmcnt(32)" ::: "memory");
            __syncthreads();
        }
    }
}

extern "C" void kernel_launch(void* const* d_in, const int* in_sizes, int n_in,
                              void* d_out, int out_size, void* d_ws, size_t ws_size,
                              hipStream_t stream) {
    const float* x        = (const float*)d_in[0];
    const float* prior    = (const float*)d_in[1];
    const float* w_qkv    = (const float*)d_in[2];
    const float* w_dw     = (const float*)d_in[3];
    const float* w_proj   = (const float*)d_in[4];
    const float* w_kernel = (const float*)d_in[5];
    const float* temp     = (const float*)d_in[6];
    char* ws = (char*)d_ws;
    float*  kv    = (float*)(ws + OFF_KV);
    float*  ssq   = (float*)(ws + OFF_SSQ);
    float*  S     = (float*)(ws + OFF_S);
    __bf16* Wb    = (__bf16*)(ws + OFF_WB);
    __bf16* M     = (__bf16*)(ws + OFF_M);
    __bf16* xt    = (__bf16*)(ws + OFF_XT);
    __bf16* qkv2  = (__bf16*)(ws + OFF_XT);    // aliases xt (xt dead after k_qkv)
    __bf16* qkv1  = (__bf16*)(ws + OFF_QKV1);
    float*  outp  = (float*)d_out;

    k_prep<<<432, 256, 0, stream>>>(prior, w_kernel, w_qkv, kv, (float*)(ws + OFF_SSQ), Wb);
    k_xt<<<dim3(128, 8), 256, 0, stream>>>(x, kv, xt);
    k_qkv<<<dim3(128, 8), 256, 0, stream>>>(xt, Wb, qkv1);
    k_dw<<<9216, 256, 0, stream>>>(qkv1, w_dw, qkv2, ssq);
    k_sdot<<<dim3(32, 4, 8), 256, 0, stream>>>(qkv2, S);
    k_soft<<<32, 256, 0, stream>>>(S, ssq, temp, w_proj, M);
    k_out<<<dim3(128, 8), 256, 0, stream>>>(M, qkv2, outp);
}